// Round 22
// baseline (66.955 us; speedup 1.0000x reference)
//
#include <hip/hip_runtime.h>
#include <hip/hip_bf16.h>
#include <math.h>

#define SLOPE 0.1f
#define B_ 16
#define C_ 64
#define H_ 160
#define W_ 160
#define HW_ (H_*W_)

typedef short bf16x8 __attribute__((ext_vector_type(8)));
typedef float f32x4  __attribute__((ext_vector_type(4)));
typedef unsigned int uint2v __attribute__((ext_vector_type(2)));

__device__ __forceinline__ float lrelu(float x) { return fmaxf(x, SLOPE * x); }
__device__ __forceinline__ unsigned f2bf(float x) {
  union { float f; unsigned u; } c; c.f = x;
  return (c.u + 0x7fffu + ((c.u >> 16) & 1u)) >> 16;
}
__device__ __forceinline__ float bf2f(unsigned short u) {
  union { unsigned u; float f; } c; c.u = ((unsigned)u) << 16; return c.f;
}

__device__ __forceinline__ void gl2lds16(const void* g, void* l) {
  __builtin_amdgcn_global_load_lds(
      (const __attribute__((address_space(1))) void*)g,
      (__attribute__((address_space(3))) void*)l, 16, 0, 0);
}

// ws layout: [0,1024) floats: att[b][c];
// bytes [4096, 4096+16*1536): k bf16 [b][64 slots][12] (9 used, 3 pad), slot
// permuted so wave w's conv channels are contiguous:
//   slot(c) = ((c&15)>>2)*16 + (c>>4)*4 + (c&3)
__global__ __launch_bounds__(64) void prep_kernel(
    const float* __restrict__ deg,
    const float* __restrict__ W1,
    const float* __restrict__ W2,
    const float* __restrict__ Wd1,
    const float* __restrict__ Wd2,
    float* __restrict__ ws) {
  const int b = blockIdx.x;   // 0..15
  const int j = threadIdx.x;  // 0..63 == channel
  __shared__ float sd[64], sh[64], sa[8];
  sd[j] = deg[b * 64 + j];
  __syncthreads();

  float acc = 0.f;
  for (int i = 0; i < 64; ++i) acc = fmaf(sd[i], W1[j * 64 + i], acc);
  sh[j] = lrelu(acc);

  if (j < 8) {
    float s = 0.f;
    for (int i = 0; i < 64; ++i) s = fmaf(sd[i], Wd1[j * 64 + i], s);
    sa[j] = lrelu(s);
  }
  __syncthreads();

  float kv[9];
#pragma unroll
  for (int t = 0; t < 9; ++t) kv[t] = 0.f;
  for (int l = 0; l < 64; ++l) {
    float hl = sh[l];
#pragma unroll
    for (int t = 0; t < 9; ++t) kv[t] = fmaf(hl, W2[(j * 9 + t) * 64 + l], kv[t]);
  }
  const int slot = ((j & 15) >> 2) * 16 + (j >> 4) * 4 + (j & 3);
  unsigned short* kw = (unsigned short*)((char*)ws + 4096) + (b * 64 + slot) * 12;
#pragma unroll
  for (int t = 0; t < 9; ++t) kw[t] = (unsigned short)f2bf(kv[t]);
  kw[9] = 0; kw[10] = 0; kw[11] = 0;

  float s2 = 0.f;
#pragma unroll
  for (int r = 0; r < 8; ++r) s2 = fmaf(Wd2[j * 8 + r], sa[r], s2);
  ws[b * 64 + j] = 1.f / (1.f + __expf(-s2));
}

// R18 base + ONE structural change: T and F double-buffered -> barrier B
// deleted (barriers/tile 8 -> 4). Race-safety: each wave's MFMA(g) tr_reads
// are lgkm-retired before it reaches barrier A(g+1); conv(g+2) (next writer
// of T/F[g&1]) starts only after barrier A(g+1). S reuse stays wave-local.
// LDS = 31,232 (S) + 8,192 (T x2) + 8,192 (F x2) + 1,536 (Kl) = 49,152
// -> 3 blocks/CU. (R21 retry: fixed bottom-left tap index typo j+4 -> j+3.)
__global__ __launch_bounds__(256, 3) void main_kernel(
    const float* __restrict__ feat,
    const float* __restrict__ Wc,
    const float* __restrict__ bc,
    const float* __restrict__ ws,
    float* __restrict__ out) {
  __shared__ __align__(16) float S[2][16][244];            // 31,232 B
  __shared__ __align__(16) unsigned short Tt[4096];        //  8,192 B (2 buf)
  __shared__ __align__(16) unsigned short Ff[4096];        //  8,192 B (2 buf)
  __shared__ __align__(16) unsigned short Kl[768];         //  1,536 B

  // Chunked XCD swizzle (3200 % 8 == 0).
  const int rb  = blockIdx.x;
  const int bid = (rb & 7) * 400 + (rb >> 3);
  const int b   = bid / 200;
  const int rem = bid - b * 200;
  const int ty  = rem / 10, tx = rem - ty * 10;
  const int x0 = tx * 16, y0 = ty * 8;
  const int tid = threadIdx.x;
  const int lane = tid & 63, wid = tid >> 6;

  const float* __restrict__ attp  = ws + b * 64;
  const char*  __restrict__ kb8   = (const char*)ws + 4096 + b * 1536;
  const float* __restrict__ plane = feat + (size_t)(b * 64) * HW_;

  // conv ids
  const int ci = tid >> 4;          // = 4*wid + (lane>>4)
  const int q  = (tid >> 2) & 3;    // x-quad
  const int h  = tid & 3;           // row-pair
  // mfma ids
  const int nl = lane & 15, kg = lane >> 4;
  const int ochunk = wid * 16;

  // stage lane map: lane -> (halo row 0..9, 16B chunk 0..5); lanes 60-63 off.
  const int srow = lane / 6;
  const int schk = lane - srow * 6;
  const int grow = min(max(y0 + srow - 1, 0), H_ - 1);
  const int gcol = min(max(x0 - 4 + schk * 4, 0), W_ - 4);
  const float* sp0 = plane + grow * W_ + gcol;

  // ---- compiler-visible preloads (complete before vmcnt baseline) ----
  union AF { bf16x8 v; unsigned short u[8]; };
  AF a[4];
  const unsigned short ab = (unsigned short)f2bf(attp[ochunk + nl]);
#pragma unroll
  for (int g = 0; g < 4; ++g) {
    const float4 w = *(const float4*)(Wc + (ochunk + nl) * 64 + g * 16 + 4 * kg);
    a[g].u[0] = (unsigned short)f2bf(w.x); a[g].u[1] = (unsigned short)f2bf(w.y);
    a[g].u[2] = (unsigned short)f2bf(w.z); a[g].u[3] = (unsigned short)f2bf(w.w);
    // merged-K residual: diag(att) in upper k-half, only for this wave's group
#pragma unroll
    for (int j = 0; j < 4; ++j)
      a[g].u[4 + j] = (wid == g && nl == 4 * kg + j) ? ab : (unsigned short)0;
  }
  const float4 bcv = *(const float4*)(bc + ochunk + 4 * kg);

  asm volatile("s_waitcnt vmcnt(0)" ::: "memory");  // clean vmcnt baseline

  // ---- prologue: wave-local Kl (1 inst) + stage(0) + stage(1) ----
  if (lane < 24) gl2lds16(kb8 + wid * 384 + lane * 16, &Kl[wid * 192]);
#define STAGE(g_, bf_) \
  if (lane < 60) { \
    const float* s_ = sp0 + (size_t)((g_) * 16 + wid * 4) * HW_; \
    gl2lds16(s_,            &S[bf_][wid * 4 + 0][0]); \
    gl2lds16(s_ + HW_,      &S[bf_][wid * 4 + 1][0]); \
    gl2lds16(s_ + 2 * HW_,  &S[bf_][wid * 4 + 2][0]); \
    gl2lds16(s_ + 3 * HW_,  &S[bf_][wid * 4 + 3][0]); \
  }
  STAGE(0, 0);
  STAGE(1, 1);
  // outstanding: Kl(1) + S0(4) + S1(4) = 9

  f32x4 acc[8];
#pragma unroll
  for (int nt = 0; nt < 8; ++nt) acc[nt] = (f32x4){0.f, 0.f, 0.f, 0.f};

  // conv edge masks
  const float mlz = (x0 == 0 && q == 0) ? 0.f : 1.f;
  const float mrz = (x0 == W_ - 16 && q == 3) ? 0.f : 1.f;

  const unsigned t_base = (unsigned)(uintptr_t)&Tt[0] + (unsigned)(lane * 8);
  const unsigned f_base = (unsigned)(uintptr_t)&Ff[0] + (unsigned)(lane * 8);
  union BU { bf16x8 v; uint2v qv[2]; };

#pragma unroll
  for (int g = 0; g < 4; ++g) {
    const int sb = g & 1;
    if (g < 3) {
      asm volatile("s_waitcnt vmcnt(4)" ::: "memory");  // own stage(g) done
    } else {
      asm volatile("s_waitcnt vmcnt(0)" ::: "memory");
    }
    __builtin_amdgcn_sched_barrier(0);

    // ---- conv(g): own-wave S rows; wave-local packed Kl (12-short) ----
    const unsigned short* kr = &Kl[(wid * 16 + g * 4 + (lane >> 4)) * 12];
    union KU { uint2v v; unsigned short u[4]; };
    KU kA, kB;
    kA.v = *(const uint2v*)(kr);
    kB.v = *(const uint2v*)(kr + 4);
    const unsigned short k8u = kr[8];
    float kk[9];
#pragma unroll
    for (int t = 0; t < 4; ++t) { kk[t] = bf2f(kA.u[t]); kk[4 + t] = bf2f(kB.u[t]); }
    kk[8] = bf2f(k8u);

    float rv[4][9];
#pragma unroll
    for (int rr = 0; rr < 4; ++rr) {
      const float* sp = &S[sb][ci][(2 * h + rr) * 24 + 4 * q];
      const f32x4 v0 = *(const f32x4*)sp;
      const f32x4 v1 = *(const f32x4*)(sp + 4);
      rv[rr][0] = v0[0]; rv[rr][1] = v0[1]; rv[rr][2] = v0[2];
      rv[rr][3] = v0[3] * mlz;
      rv[rr][4] = v1[0]; rv[rr][5] = v1[1]; rv[rr][6] = v1[2]; rv[rr][7] = v1[3];
      rv[rr][8] = sp[8] * mrz;
    }

#pragma unroll
    for (int rr = 0; rr < 2; ++rr) {
      const int srw = 2 * h + rr;
      const float mt = (srw == 0 && y0 == 0) ? 0.f : 1.f;
      const float mb = (srw == 7 && y0 == H_ - 8) ? 0.f : 1.f;
      float sv[4], fv[4];
#pragma unroll
      for (int j = 0; j < 4; ++j) {
        float ts = fmaf(rv[rr][j + 5], kk[2], fmaf(rv[rr][j + 4], kk[1], rv[rr][j + 3] * kk[0]));
        float cs = fmaf(rv[rr + 1][j + 5], kk[5], fmaf(rv[rr + 1][j + 4], kk[4], rv[rr + 1][j + 3] * kk[3]));
        float bs = fmaf(rv[rr + 2][j + 5], kk[8], fmaf(rv[rr + 2][j + 4], kk[7], rv[rr + 2][j + 3] * kk[6]));
        sv[j] = fmaf(mt, ts, fmaf(mb, bs, cs));
        fv[j] = rv[rr + 1][j + 4];  // center tap
      }
      uint2v tq, fq;
      tq.x = f2bf(lrelu(sv[0])) | (f2bf(lrelu(sv[1])) << 16);
      tq.y = f2bf(lrelu(sv[2])) | (f2bf(lrelu(sv[3])) << 16);
      fq.x = f2bf(fv[0]) | (f2bf(fv[1]) << 16);
      fq.y = f2bf(fv[2]) | (f2bf(fv[3]) << 16);
      const int tidx = sb * 2048 + srw * 256 + ci * 16 + 4 * q;
      *(uint2v*)&Tt[tidx] = tq;
      *(uint2v*)&Ff[tidx] = fq;
    }

    // depth-2 stage-ahead: S[g&1] just released by this wave's conv ->
    // stage(g+2) may overwrite it now (wave-local rows only).
    if (g < 2) { STAGE(g + 2, sb); }

    asm volatile("s_waitcnt lgkmcnt(0)" ::: "memory");
    __builtin_amdgcn_sched_barrier(0);
    __builtin_amdgcn_s_barrier();            // barrier A: T/F[sb] ready
    __builtin_amdgcn_sched_barrier(0);

    const unsigned tb = t_base + (unsigned)(sb * 4096);
    const unsigned fb = f_base + (unsigned)(sb * 4096);

    if (wid == g) {
      // residual group: merged T+F reads, 4 sub-batches of {2T,2F},
      // counted lgkmcnt(4) -> window <= 8 reads (16 VGPR).
      uint2v t0, t1, t2, t3, t4, t5, t6, t7;
      uint2v f0, f1, f2, f3, f4, f5, f6, f7;
      asm volatile("ds_read_b64_tr_b16 %0, %1 offset:0"    : "=v"(t0) : "v"(tb));
      asm volatile("ds_read_b64_tr_b16 %0, %1 offset:512"  : "=v"(t1) : "v"(tb));
      asm volatile("ds_read_b64_tr_b16 %0, %1 offset:0"    : "=v"(f0) : "v"(fb));
      asm volatile("ds_read_b64_tr_b16 %0, %1 offset:512"  : "=v"(f1) : "v"(fb));
      asm volatile("ds_read_b64_tr_b16 %0, %1 offset:1024" : "=v"(t2) : "v"(tb));
      asm volatile("ds_read_b64_tr_b16 %0, %1 offset:1536" : "=v"(t3) : "v"(tb));
      asm volatile("ds_read_b64_tr_b16 %0, %1 offset:1024" : "=v"(f2) : "v"(fb));
      asm volatile("ds_read_b64_tr_b16 %0, %1 offset:1536" : "=v"(f3) : "v"(fb));
      asm volatile("s_waitcnt lgkmcnt(4)" ::: "memory");
      __builtin_amdgcn_sched_barrier(0);
      {
        BU u0, u1;
        u0.qv[0] = t0; u0.qv[1] = f0;
        u1.qv[0] = t1; u1.qv[1] = f1;
        acc[0] = __builtin_amdgcn_mfma_f32_16x16x32_bf16(a[g].v, u0.v, acc[0], 0, 0, 0);
        acc[1] = __builtin_amdgcn_mfma_f32_16x16x32_bf16(a[g].v, u1.v, acc[1], 0, 0, 0);
      }
      asm volatile("ds_read_b64_tr_b16 %0, %1 offset:2048" : "=v"(t4) : "v"(tb));
      asm volatile("ds_read_b64_tr_b16 %0, %1 offset:2560" : "=v"(t5) : "v"(tb));
      asm volatile("ds_read_b64_tr_b16 %0, %1 offset:2048" : "=v"(f4) : "v"(fb));
      asm volatile("ds_read_b64_tr_b16 %0, %1 offset:2560" : "=v"(f5) : "v"(fb));
      asm volatile("s_waitcnt lgkmcnt(4)" ::: "memory");
      __builtin_amdgcn_sched_barrier(0);
      {
        BU u2, u3;
        u2.qv[0] = t2; u2.qv[1] = f2;
        u3.qv[0] = t3; u3.qv[1] = f3;
        acc[2] = __builtin_amdgcn_mfma_f32_16x16x32_bf16(a[g].v, u2.v, acc[2], 0, 0, 0);
        acc[3] = __builtin_amdgcn_mfma_f32_16x16x32_bf16(a[g].v, u3.v, acc[3], 0, 0, 0);
      }
      asm volatile("ds_read_b64_tr_b16 %0, %1 offset:3072" : "=v"(t6) : "v"(tb));
      asm volatile("ds_read_b64_tr_b16 %0, %1 offset:3584" : "=v"(t7) : "v"(tb));
      asm volatile("ds_read_b64_tr_b16 %0, %1 offset:3072" : "=v"(f6) : "v"(fb));
      asm volatile("ds_read_b64_tr_b16 %0, %1 offset:3584" : "=v"(f7) : "v"(fb));
      asm volatile("s_waitcnt lgkmcnt(4)" ::: "memory");
      __builtin_amdgcn_sched_barrier(0);
      {
        BU u4, u5;
        u4.qv[0] = t4; u4.qv[1] = f4;
        u5.qv[0] = t5; u5.qv[1] = f5;
        acc[4] = __builtin_amdgcn_mfma_f32_16x16x32_bf16(a[g].v, u4.v, acc[4], 0, 0, 0);
        acc[5] = __builtin_amdgcn_mfma_f32_16x16x32_bf16(a[g].v, u5.v, acc[5], 0, 0, 0);
      }
      asm volatile("s_waitcnt lgkmcnt(0)" ::: "memory");
      __builtin_amdgcn_sched_barrier(0);
      {
        BU u6, u7;
        u6.qv[0] = t6; u6.qv[1] = f6;
        u7.qv[0] = t7; u7.qv[1] = f7;
        acc[6] = __builtin_amdgcn_mfma_f32_16x16x32_bf16(a[g].v, u6.v, acc[6], 0, 0, 0);
        acc[7] = __builtin_amdgcn_mfma_f32_16x16x32_bf16(a[g].v, u7.v, acc[7], 0, 0, 0);
      }
    } else {
      // non-residual group: two-batch T reads, zero upper k-half
      uint2v ta0, ta1, ta2, ta3, tb0, tb1, tb2, tb3;
      asm volatile("ds_read_b64_tr_b16 %0, %1 offset:0"    : "=v"(ta0) : "v"(tb));
      asm volatile("ds_read_b64_tr_b16 %0, %1 offset:512"  : "=v"(ta1) : "v"(tb));
      asm volatile("ds_read_b64_tr_b16 %0, %1 offset:1024" : "=v"(ta2) : "v"(tb));
      asm volatile("ds_read_b64_tr_b16 %0, %1 offset:1536" : "=v"(ta3) : "v"(tb));
      asm volatile("s_waitcnt lgkmcnt(0)" ::: "memory");
      __builtin_amdgcn_sched_barrier(0);
      asm volatile("ds_read_b64_tr_b16 %0, %1 offset:2048" : "=v"(tb0) : "v"(tb));
      asm volatile("ds_read_b64_tr_b16 %0, %1 offset:2560" : "=v"(tb1) : "v"(tb));
      asm volatile("ds_read_b64_tr_b16 %0, %1 offset:3072" : "=v"(tb2) : "v"(tb));
      asm volatile("ds_read_b64_tr_b16 %0, %1 offset:3584" : "=v"(tb3) : "v"(tb));
      {
        BU u0, u1, u2, u3;
        u0.qv[0] = ta0; u0.qv[1] = (uint2v){0u, 0u};
        u1.qv[0] = ta1; u1.qv[1] = (uint2v){0u, 0u};
        u2.qv[0] = ta2; u2.qv[1] = (uint2v){0u, 0u};
        u3.qv[0] = ta3; u3.qv[1] = (uint2v){0u, 0u};
        acc[0] = __builtin_amdgcn_mfma_f32_16x16x32_bf16(a[g].v, u0.v, acc[0], 0, 0, 0);
        acc[1] = __builtin_amdgcn_mfma_f32_16x16x32_bf16(a[g].v, u1.v, acc[1], 0, 0, 0);
        acc[2] = __builtin_amdgcn_mfma_f32_16x16x32_bf16(a[g].v, u2.v, acc[2], 0, 0, 0);
        acc[3] = __builtin_amdgcn_mfma_f32_16x16x32_bf16(a[g].v, u3.v, acc[3], 0, 0, 0);
      }
      asm volatile("s_waitcnt lgkmcnt(0)" ::: "memory");
      __builtin_amdgcn_sched_barrier(0);
      {
        BU u4, u5, u6, u7;
        u4.qv[0] = tb0; u4.qv[1] = (uint2v){0u, 0u};
        u5.qv[0] = tb1; u5.qv[1] = (uint2v){0u, 0u};
        u6.qv[0] = tb2; u6.qv[1] = (uint2v){0u, 0u};
        u7.qv[0] = tb3; u7.qv[1] = (uint2v){0u, 0u};
        acc[4] = __builtin_amdgcn_mfma_f32_16x16x32_bf16(a[g].v, u4.v, acc[4], 0, 0, 0);
        acc[5] = __builtin_amdgcn_mfma_f32_16x16x32_bf16(a[g].v, u5.v, acc[5], 0, 0, 0);
        acc[6] = __builtin_amdgcn_mfma_f32_16x16x32_bf16(a[g].v, u6.v, acc[6], 0, 0, 0);
        acc[7] = __builtin_amdgcn_mfma_f32_16x16x32_bf16(a[g].v, u7.v, acc[7], 0, 0, 0);
      }
    }
    // no barrier B: T/F double-buffered; next writer of this buffer is
    // conv(g+2), which every wave reaches only after barrier A(g+1).
  }
#undef STAGE

  // ---- epilogue: + bias, store (residual already in acc via merged-K) ----
  const int ob = ochunk + 4 * kg;
  float* __restrict__ outb = out + (size_t)(b * 64) * HW_;
#pragma unroll
  for (int nt = 0; nt < 8; ++nt) {
    const int off = (y0 + nt) * W_ + x0 + nl;
    outb[(size_t)(ob + 0) * HW_ + off] = acc[nt][0] + bcv.x;
    outb[(size_t)(ob + 1) * HW_ + off] = acc[nt][1] + bcv.y;
    outb[(size_t)(ob + 2) * HW_ + off] = acc[nt][2] + bcv.z;
    outb[(size_t)(ob + 3) * HW_ + off] = acc[nt][3] + bcv.w;
  }
}

extern "C" void kernel_launch(void* const* d_in, const int* in_sizes, int n_in,
                              void* d_out, int out_size, void* d_ws, size_t ws_size,
                              hipStream_t stream) {
  const float* feat = (const float*)d_in[0];
  const float* deg  = (const float*)d_in[1];
  const float* W1   = (const float*)d_in[2];
  const float* W2   = (const float*)d_in[3];
  const float* Wc   = (const float*)d_in[4];
  const float* bc   = (const float*)d_in[5];
  const float* Wd1  = (const float*)d_in[6];
  const float* Wd2  = (const float*)d_in[7];
  float* out = (float*)d_out;
  float* ws  = (float*)d_ws;

  prep_kernel<<<dim3(B_), dim3(64), 0, stream>>>(deg, W1, W2, Wd1, Wd2, ws);
  main_kernel<<<dim3(3200), dim3(256), 0, stream>>>(feat, Wc, bc, ws, out);
}

// Round 23
// 65.778 us; speedup vs baseline: 1.0179x; 1.0179x over previous
//
#include <hip/hip_runtime.h>
#include <hip/hip_bf16.h>
#include <math.h>

#define SLOPE 0.1f
#define B_ 16
#define C_ 64
#define H_ 160
#define W_ 160
#define HW_ (H_*W_)

typedef short bf16x8 __attribute__((ext_vector_type(8)));
typedef float f32x4  __attribute__((ext_vector_type(4)));
typedef unsigned int uint2v __attribute__((ext_vector_type(2)));

__device__ __forceinline__ float lrelu(float x) { return fmaxf(x, SLOPE * x); }
__device__ __forceinline__ unsigned f2bf(float x) {
  union { float f; unsigned u; } c; c.f = x;
  return (c.u + 0x7fffu + ((c.u >> 16) & 1u)) >> 16;
}
__device__ __forceinline__ float bf2f(unsigned short u) {
  union { unsigned u; float f; } c; c.u = ((unsigned)u) << 16; return c.f;
}

__device__ __forceinline__ void gl2lds16(const void* g, void* l) {
  __builtin_amdgcn_global_load_lds(
      (const __attribute__((address_space(1))) void*)g,
      (__attribute__((address_space(3))) void*)l, 16, 0, 0);
}

// ws layout: [0,1024) floats: att[b][c];
// bytes [4096, 4096+16*1536): k bf16 [b][64 slots][12] (9 used, 3 pad), slot
// permuted so wave w's conv channels are contiguous:
//   slot(c) = ((c&15)>>2)*16 + (c>>4)*4 + (c&3)
__global__ __launch_bounds__(64) void prep_kernel(
    const float* __restrict__ deg,
    const float* __restrict__ W1,
    const float* __restrict__ W2,
    const float* __restrict__ Wd1,
    const float* __restrict__ Wd2,
    float* __restrict__ ws) {
  const int b = blockIdx.x;   // 0..15
  const int j = threadIdx.x;  // 0..63 == channel
  __shared__ float sd[64], sh[64], sa[8];
  sd[j] = deg[b * 64 + j];
  __syncthreads();

  float acc = 0.f;
  for (int i = 0; i < 64; ++i) acc = fmaf(sd[i], W1[j * 64 + i], acc);
  sh[j] = lrelu(acc);

  if (j < 8) {
    float s = 0.f;
    for (int i = 0; i < 64; ++i) s = fmaf(sd[i], Wd1[j * 64 + i], s);
    sa[j] = lrelu(s);
  }
  __syncthreads();

  float kv[9];
#pragma unroll
  for (int t = 0; t < 9; ++t) kv[t] = 0.f;
  for (int l = 0; l < 64; ++l) {
    float hl = sh[l];
#pragma unroll
    for (int t = 0; t < 9; ++t) kv[t] = fmaf(hl, W2[(j * 9 + t) * 64 + l], kv[t]);
  }
  const int slot = ((j & 15) >> 2) * 16 + (j >> 4) * 4 + (j & 3);
  unsigned short* kw = (unsigned short*)((char*)ws + 4096) + (b * 64 + slot) * 12;
#pragma unroll
  for (int t = 0; t < 9; ++t) kw[t] = (unsigned short)f2bf(kv[t]);
  kw[9] = 0; kw[10] = 0; kw[11] = 0;

  float s2 = 0.f;
#pragma unroll
  for (int r = 0; r < 8; ++r) s2 = fmaf(Wd2[j * 8 + r], sa[r], s2);
  ws[b * 64 + j] = 1.f / (1.f + __expf(-s2));
}

// FINAL (R18/R20, session best 65.9 us): 8x16 tile, 4 channel-groups of 16.
// S double-buffered via global_load_lds, stride 244 words (bank de-alias);
// wave-local stage->conv ordered by vmcnt alone; depth-2 stage-ahead;
// wave-local packed Kl (12-short); 2 barriers/group; two-batch tr_reads;
// merged-K residual: diag(att) in upper A k-half at group==wid, F through
// B upper half. LDS = 31,232 + 4,096 + 4,096 + 1,536 = 40,960 -> 4 blk/CU.
__global__ __launch_bounds__(256, 4) void main_kernel(
    const float* __restrict__ feat,
    const float* __restrict__ Wc,
    const float* __restrict__ bc,
    const float* __restrict__ ws,
    float* __restrict__ out) {
  __shared__ __align__(16) float S[2][16][244];            // 31,232 B
  __shared__ __align__(16) unsigned short Tt[2048];        //  4,096 B
  __shared__ __align__(16) unsigned short Ff[2048];        //  4,096 B
  __shared__ __align__(16) unsigned short Kl[768];         //  1,536 B

  // Chunked XCD swizzle (3200 % 8 == 0).
  const int rb  = blockIdx.x;
  const int bid = (rb & 7) * 400 + (rb >> 3);
  const int b   = bid / 200;
  const int rem = bid - b * 200;
  const int ty  = rem / 10, tx = rem - ty * 10;
  const int x0 = tx * 16, y0 = ty * 8;
  const int tid = threadIdx.x;
  const int lane = tid & 63, wid = tid >> 6;

  const float* __restrict__ attp  = ws + b * 64;
  const char*  __restrict__ kb8   = (const char*)ws + 4096 + b * 1536;
  const float* __restrict__ plane = feat + (size_t)(b * 64) * HW_;

  // conv ids
  const int ci = tid >> 4;          // = 4*wid + (lane>>4)
  const int q  = (tid >> 2) & 3;    // x-quad
  const int h  = tid & 3;           // row-pair
  // mfma ids
  const int nl = lane & 15, kg = lane >> 4;
  const int ochunk = wid * 16;

  // stage lane map: lane -> (halo row 0..9, 16B chunk 0..5); lanes 60-63 off.
  const int srow = lane / 6;
  const int schk = lane - srow * 6;
  const int grow = min(max(y0 + srow - 1, 0), H_ - 1);
  const int gcol = min(max(x0 - 4 + schk * 4, 0), W_ - 4);
  const float* sp0 = plane + grow * W_ + gcol;

  // ---- compiler-visible preloads (complete before vmcnt baseline) ----
  union AF { bf16x8 v; unsigned short u[8]; };
  AF a[4];
  const unsigned short ab = (unsigned short)f2bf(attp[ochunk + nl]);
#pragma unroll
  for (int g = 0; g < 4; ++g) {
    const float4 w = *(const float4*)(Wc + (ochunk + nl) * 64 + g * 16 + 4 * kg);
    a[g].u[0] = (unsigned short)f2bf(w.x); a[g].u[1] = (unsigned short)f2bf(w.y);
    a[g].u[2] = (unsigned short)f2bf(w.z); a[g].u[3] = (unsigned short)f2bf(w.w);
    // merged-K residual: diag(att) in upper k-half, only for this wave's group
#pragma unroll
    for (int j = 0; j < 4; ++j)
      a[g].u[4 + j] = (wid == g && nl == 4 * kg + j) ? ab : (unsigned short)0;
  }
  const float4 bcv = *(const float4*)(bc + ochunk + 4 * kg);

  asm volatile("s_waitcnt vmcnt(0)" ::: "memory");  // clean vmcnt baseline

  // ---- prologue: wave-local Kl (1 inst) + stage(0) + stage(1) ----
  if (lane < 24) gl2lds16(kb8 + wid * 384 + lane * 16, &Kl[wid * 192]);
#define STAGE(g_, bf_) \
  if (lane < 60) { \
    const float* s_ = sp0 + (size_t)((g_) * 16 + wid * 4) * HW_; \
    gl2lds16(s_,            &S[bf_][wid * 4 + 0][0]); \
    gl2lds16(s_ + HW_,      &S[bf_][wid * 4 + 1][0]); \
    gl2lds16(s_ + 2 * HW_,  &S[bf_][wid * 4 + 2][0]); \
    gl2lds16(s_ + 3 * HW_,  &S[bf_][wid * 4 + 3][0]); \
  }
  STAGE(0, 0);
  STAGE(1, 1);
  // outstanding: Kl(1) + S0(4) + S1(4) = 9

  f32x4 acc[8];
#pragma unroll
  for (int nt = 0; nt < 8; ++nt) acc[nt] = (f32x4){0.f, 0.f, 0.f, 0.f};

  // conv edge masks
  const float mlz = (x0 == 0 && q == 0) ? 0.f : 1.f;
  const float mrz = (x0 == W_ - 16 && q == 3) ? 0.f : 1.f;

  const unsigned t_base = (unsigned)(uintptr_t)&Tt[0] + (unsigned)(lane * 8);
  const unsigned f_base = (unsigned)(uintptr_t)&Ff[0] + (unsigned)(lane * 8);
  union BU { bf16x8 v; uint2v qv[2]; };

#pragma unroll
  for (int g = 0; g < 4; ++g) {
    const int sb = g & 1;
    if (g < 3) {
      asm volatile("s_waitcnt vmcnt(4)" ::: "memory");  // own stage(g) done
    } else {
      asm volatile("s_waitcnt vmcnt(0)" ::: "memory");
    }
    __builtin_amdgcn_sched_barrier(0);

    // ---- conv(g): own-wave S rows; wave-local packed Kl (12-short) ----
    const unsigned short* kr = &Kl[(wid * 16 + g * 4 + (lane >> 4)) * 12];
    union KU { uint2v v; unsigned short u[4]; };
    KU kA, kB;
    kA.v = *(const uint2v*)(kr);
    kB.v = *(const uint2v*)(kr + 4);
    const unsigned short k8u = kr[8];
    float kk[9];
#pragma unroll
    for (int t = 0; t < 4; ++t) { kk[t] = bf2f(kA.u[t]); kk[4 + t] = bf2f(kB.u[t]); }
    kk[8] = bf2f(k8u);

    float rv[4][9];
#pragma unroll
    for (int rr = 0; rr < 4; ++rr) {
      const float* sp = &S[sb][ci][(2 * h + rr) * 24 + 4 * q];
      const f32x4 v0 = *(const f32x4*)sp;
      const f32x4 v1 = *(const f32x4*)(sp + 4);
      rv[rr][0] = v0[0]; rv[rr][1] = v0[1]; rv[rr][2] = v0[2];
      rv[rr][3] = v0[3] * mlz;
      rv[rr][4] = v1[0]; rv[rr][5] = v1[1]; rv[rr][6] = v1[2]; rv[rr][7] = v1[3];
      rv[rr][8] = sp[8] * mrz;
    }

#pragma unroll
    for (int rr = 0; rr < 2; ++rr) {
      const int srw = 2 * h + rr;
      const float mt = (srw == 0 && y0 == 0) ? 0.f : 1.f;
      const float mb = (srw == 7 && y0 == H_ - 8) ? 0.f : 1.f;
      float sv[4], fv[4];
#pragma unroll
      for (int j = 0; j < 4; ++j) {
        float ts = fmaf(rv[rr][j + 5], kk[2], fmaf(rv[rr][j + 4], kk[1], rv[rr][j + 3] * kk[0]));
        float cs = fmaf(rv[rr + 1][j + 5], kk[5], fmaf(rv[rr + 1][j + 4], kk[4], rv[rr + 1][j + 3] * kk[3]));
        float bs = fmaf(rv[rr + 2][j + 5], kk[8], fmaf(rv[rr + 2][j + 4], kk[7], rv[rr + 2][j + 3] * kk[6]));
        sv[j] = fmaf(mt, ts, fmaf(mb, bs, cs));
        fv[j] = rv[rr + 1][j + 4];  // center tap
      }
      uint2v tq, fq;
      tq.x = f2bf(lrelu(sv[0])) | (f2bf(lrelu(sv[1])) << 16);
      tq.y = f2bf(lrelu(sv[2])) | (f2bf(lrelu(sv[3])) << 16);
      fq.x = f2bf(fv[0]) | (f2bf(fv[1]) << 16);
      fq.y = f2bf(fv[2]) | (f2bf(fv[3]) << 16);
      const int tidx = srw * 256 + ci * 16 + 4 * q;
      *(uint2v*)&Tt[tidx] = tq;
      *(uint2v*)&Ff[tidx] = fq;
    }

    // depth-2 stage-ahead: S[g&1] just released by this wave's conv ->
    // stage(g+2) may overwrite it now (wave-local rows only).
    if (g < 2) { STAGE(g + 2, sb); }

    asm volatile("s_waitcnt lgkmcnt(0)" ::: "memory");
    __builtin_amdgcn_sched_barrier(0);
    __builtin_amdgcn_s_barrier();            // barrier A: T/F ready
    __builtin_amdgcn_sched_barrier(0);

    if (wid == g) {
      // residual group: merged T+F reads, 4 sub-batches of {2T,2F},
      // counted lgkmcnt(4) -> window <= 8 reads (16 VGPR).
      uint2v t0, t1, t2, t3, t4, t5, t6, t7;
      uint2v f0, f1, f2, f3, f4, f5, f6, f7;
      asm volatile("ds_read_b64_tr_b16 %0, %1 offset:0"    : "=v"(t0) : "v"(t_base));
      asm volatile("ds_read_b64_tr_b16 %0, %1 offset:512"  : "=v"(t1) : "v"(t_base));
      asm volatile("ds_read_b64_tr_b16 %0, %1 offset:0"    : "=v"(f0) : "v"(f_base));
      asm volatile("ds_read_b64_tr_b16 %0, %1 offset:512"  : "=v"(f1) : "v"(f_base));
      asm volatile("ds_read_b64_tr_b16 %0, %1 offset:1024" : "=v"(t2) : "v"(t_base));
      asm volatile("ds_read_b64_tr_b16 %0, %1 offset:1536" : "=v"(t3) : "v"(t_base));
      asm volatile("ds_read_b64_tr_b16 %0, %1 offset:1024" : "=v"(f2) : "v"(f_base));
      asm volatile("ds_read_b64_tr_b16 %0, %1 offset:1536" : "=v"(f3) : "v"(f_base));
      asm volatile("s_waitcnt lgkmcnt(4)" ::: "memory");
      __builtin_amdgcn_sched_barrier(0);
      {
        BU u0, u1;
        u0.qv[0] = t0; u0.qv[1] = f0;
        u1.qv[0] = t1; u1.qv[1] = f1;
        acc[0] = __builtin_amdgcn_mfma_f32_16x16x32_bf16(a[g].v, u0.v, acc[0], 0, 0, 0);
        acc[1] = __builtin_amdgcn_mfma_f32_16x16x32_bf16(a[g].v, u1.v, acc[1], 0, 0, 0);
      }
      asm volatile("ds_read_b64_tr_b16 %0, %1 offset:2048" : "=v"(t4) : "v"(t_base));
      asm volatile("ds_read_b64_tr_b16 %0, %1 offset:2560" : "=v"(t5) : "v"(t_base));
      asm volatile("ds_read_b64_tr_b16 %0, %1 offset:2048" : "=v"(f4) : "v"(f_base));
      asm volatile("ds_read_b64_tr_b16 %0, %1 offset:2560" : "=v"(f5) : "v"(f_base));
      asm volatile("s_waitcnt lgkmcnt(4)" ::: "memory");
      __builtin_amdgcn_sched_barrier(0);
      {
        BU u2, u3;
        u2.qv[0] = t2; u2.qv[1] = f2;
        u3.qv[0] = t3; u3.qv[1] = f3;
        acc[2] = __builtin_amdgcn_mfma_f32_16x16x32_bf16(a[g].v, u2.v, acc[2], 0, 0, 0);
        acc[3] = __builtin_amdgcn_mfma_f32_16x16x32_bf16(a[g].v, u3.v, acc[3], 0, 0, 0);
      }
      asm volatile("ds_read_b64_tr_b16 %0, %1 offset:3072" : "=v"(t6) : "v"(t_base));
      asm volatile("ds_read_b64_tr_b16 %0, %1 offset:3584" : "=v"(t7) : "v"(t_base));
      asm volatile("ds_read_b64_tr_b16 %0, %1 offset:3072" : "=v"(f6) : "v"(f_base));
      asm volatile("ds_read_b64_tr_b16 %0, %1 offset:3584" : "=v"(f7) : "v"(f_base));
      asm volatile("s_waitcnt lgkmcnt(4)" ::: "memory");
      __builtin_amdgcn_sched_barrier(0);
      {
        BU u4, u5;
        u4.qv[0] = t4; u4.qv[1] = f4;
        u5.qv[0] = t5; u5.qv[1] = f5;
        acc[4] = __builtin_amdgcn_mfma_f32_16x16x32_bf16(a[g].v, u4.v, acc[4], 0, 0, 0);
        acc[5] = __builtin_amdgcn_mfma_f32_16x16x32_bf16(a[g].v, u5.v, acc[5], 0, 0, 0);
      }
      asm volatile("s_waitcnt lgkmcnt(0)" ::: "memory");
      __builtin_amdgcn_sched_barrier(0);
      {
        BU u6, u7;
        u6.qv[0] = t6; u6.qv[1] = f6;
        u7.qv[0] = t7; u7.qv[1] = f7;
        acc[6] = __builtin_amdgcn_mfma_f32_16x16x32_bf16(a[g].v, u6.v, acc[6], 0, 0, 0);
        acc[7] = __builtin_amdgcn_mfma_f32_16x16x32_bf16(a[g].v, u7.v, acc[7], 0, 0, 0);
      }
    } else {
      // non-residual group: two-batch T reads, zero upper k-half
      uint2v ta0, ta1, ta2, ta3, tb0, tb1, tb2, tb3;
      asm volatile("ds_read_b64_tr_b16 %0, %1 offset:0"    : "=v"(ta0) : "v"(t_base));
      asm volatile("ds_read_b64_tr_b16 %0, %1 offset:512"  : "=v"(ta1) : "v"(t_base));
      asm volatile("ds_read_b64_tr_b16 %0, %1 offset:1024" : "=v"(ta2) : "v"(t_base));
      asm volatile("ds_read_b64_tr_b16 %0, %1 offset:1536" : "=v"(ta3) : "v"(t_base));
      asm volatile("s_waitcnt lgkmcnt(0)" ::: "memory");
      __builtin_amdgcn_sched_barrier(0);
      asm volatile("ds_read_b64_tr_b16 %0, %1 offset:2048" : "=v"(tb0) : "v"(t_base));
      asm volatile("ds_read_b64_tr_b16 %0, %1 offset:2560" : "=v"(tb1) : "v"(t_base));
      asm volatile("ds_read_b64_tr_b16 %0, %1 offset:3072" : "=v"(tb2) : "v"(t_base));
      asm volatile("ds_read_b64_tr_b16 %0, %1 offset:3584" : "=v"(tb3) : "v"(t_base));
      {
        BU u0, u1, u2, u3;
        u0.qv[0] = ta0; u0.qv[1] = (uint2v){0u, 0u};
        u1.qv[0] = ta1; u1.qv[1] = (uint2v){0u, 0u};
        u2.qv[0] = ta2; u2.qv[1] = (uint2v){0u, 0u};
        u3.qv[0] = ta3; u3.qv[1] = (uint2v){0u, 0u};
        acc[0] = __builtin_amdgcn_mfma_f32_16x16x32_bf16(a[g].v, u0.v, acc[0], 0, 0, 0);
        acc[1] = __builtin_amdgcn_mfma_f32_16x16x32_bf16(a[g].v, u1.v, acc[1], 0, 0, 0);
        acc[2] = __builtin_amdgcn_mfma_f32_16x16x32_bf16(a[g].v, u2.v, acc[2], 0, 0, 0);
        acc[3] = __builtin_amdgcn_mfma_f32_16x16x32_bf16(a[g].v, u3.v, acc[3], 0, 0, 0);
      }
      asm volatile("s_waitcnt lgkmcnt(0)" ::: "memory");
      __builtin_amdgcn_sched_barrier(0);
      {
        BU u4, u5, u6, u7;
        u4.qv[0] = tb0; u4.qv[1] = (uint2v){0u, 0u};
        u5.qv[0] = tb1; u5.qv[1] = (uint2v){0u, 0u};
        u6.qv[0] = tb2; u6.qv[1] = (uint2v){0u, 0u};
        u7.qv[0] = tb3; u7.qv[1] = (uint2v){0u, 0u};
        acc[4] = __builtin_amdgcn_mfma_f32_16x16x32_bf16(a[g].v, u4.v, acc[4], 0, 0, 0);
        acc[5] = __builtin_amdgcn_mfma_f32_16x16x32_bf16(a[g].v, u5.v, acc[5], 0, 0, 0);
        acc[6] = __builtin_amdgcn_mfma_f32_16x16x32_bf16(a[g].v, u6.v, acc[6], 0, 0, 0);
        acc[7] = __builtin_amdgcn_mfma_f32_16x16x32_bf16(a[g].v, u7.v, acc[7], 0, 0, 0);
      }
    }
    __builtin_amdgcn_s_barrier();            // barrier B: T/F safe to reuse
    __builtin_amdgcn_sched_barrier(0);
  }
#undef STAGE

  // ---- epilogue: + bias, store (residual already in acc via merged-K) ----
  const int ob = ochunk + 4 * kg;
  float* __restrict__ outb = out + (size_t)(b * 64) * HW_;
#pragma unroll
  for (int nt = 0; nt < 8; ++nt) {
    const int off = (y0 + nt) * W_ + x0 + nl;
    outb[(size_t)(ob + 0) * HW_ + off] = acc[nt][0] + bcv.x;
    outb[(size_t)(ob + 1) * HW_ + off] = acc[nt][1] + bcv.y;
    outb[(size_t)(ob + 2) * HW_ + off] = acc[nt][2] + bcv.z;
    outb[(size_t)(ob + 3) * HW_ + off] = acc[nt][3] + bcv.w;
  }
}

extern "C" void kernel_launch(void* const* d_in, const int* in_sizes, int n_in,
                              void* d_out, int out_size, void* d_ws, size_t ws_size,
                              hipStream_t stream) {
  const float* feat = (const float*)d_in[0];
  const float* deg  = (const float*)d_in[1];
  const float* W1   = (const float*)d_in[2];
  const float* W2   = (const float*)d_in[3];
  const float* Wc   = (const float*)d_in[4];
  const float* bc   = (const float*)d_in[5];
  const float* Wd1  = (const float*)d_in[6];
  const float* Wd2  = (const float*)d_in[7];
  float* out = (float*)d_out;
  float* ws  = (float*)d_ws;

  prep_kernel<<<dim3(B_), dim3(64), 0, stream>>>(deg, W1, W2, Wd1, Wd2, ws);
  main_kernel<<<dim3(3200), dim3(256), 0, stream>>>(feat, Wc, bc, ws, out);
}